// Round 11
// baseline (204.751 us; speedup 1.0000x reference)
//
#include <hip/hip_runtime.h>
#include <hip/hip_bf16.h>
#include <math.h>

#define TV_ 1600
#define SCALE_K 2.885390081777927f
#define RS2_ 0.70710678118654752f

typedef __attribute__((ext_vector_type(8))) short bf16x8;
typedef __attribute__((ext_vector_type(4))) float f32x4;
typedef __attribute__((ext_vector_type(2))) __fp16 h2f;

union F4H { float4 f; h2f h[4]; };
union F2H { float2 f; h2f h[2]; };

// clamp-free tanh on pre-scaled input y = x * 2/ln2:
// tanh(x) = 1 - 2/(2^y + 1); exp2(+big)=inf -> rcp=0 -> 1; exp2(-big)=0 -> rcp(1)=1 -> -1
__device__ __forceinline__ float tanh4(float y) {
    float e = __builtin_amdgcn_exp2f(y);
    float r = __builtin_amdgcn_rcpf(e + 1.f);
    return __builtin_fmaf(-2.f, r, 1.f);
}

__device__ __forceinline__ float dot2f(h2f a, h2f b, float c) {
    return __builtin_amdgcn_fdot2(a, b, c, false);
}

__device__ __forceinline__ ushort f2bf(float f) {
    __hip_bfloat16 h = __float2bfloat16(f);
    return *(ushort*)&h;
}
__device__ __forceinline__ float bf2f(ushort u) {
    uint w = ((uint)u) << 16;
    return __uint_as_float(w);
}

// ---------------------------------------------------------------------------
// T1: bx<25 transpose -> rt + Sp partials via LDS column-reduce; bx==25 prep;
// bx==26 edge sums Tt. x loads vectorized to float4 (G13); smt stride 66
// (bank-tuned) untouched.
// ---------------------------------------------------------------------------
__global__ __launch_bounds__(256) void t1_kernel(
    const float* __restrict__ x, const float* __restrict__ pe,
    const float* __restrict__ tcn_w, const float* __restrict__ tg,
    const float* __restrict__ qkv_w, const float* __restrict__ qkv_b,
    const float* __restrict__ dbg, const float* __restrict__ dbb,
    ushort* __restrict__ rt, float* __restrict__ Sp, float* __restrict__ Tt,
    ushort* __restrict__ wb, ushort* __restrict__ wq, float* __restrict__ qb,
    ushort* __restrict__ pet, float* __restrict__ dbs)
{
    const int tid = threadIdx.x;
    const int bx = blockIdx.x, by = blockIdx.y;

    if (bx == 25) {
        #pragma unroll 1
        for (int j = 0; j < 9; ++j) {
            int idx = by * 256 + tid + j * 16384;
            if (idx < 27648) {
                int oc = idx / 576, kk = idx - oc * 576;
                int kt = kk >> 6, ci = kk & 63;
                float a = tg[oc] * rsqrtf(1.f + 1e-5f);
                wb[idx] = f2bf(tcn_w[(oc * 64 + ci) * 9 + kt] * a);
            } else if (idx < 32768) {
                int i2 = idx - 27648;
                int r = i2 >> 6, c = i2 & 63;
                int src; float sc;
                if (r < 16)      { src = r;      sc = RS2_; }
                else if (r < 32) { src = r;      sc = SCALE_K; }
                else if (r < 48) { src = r + 16; sc = 1.f; }
                else if (r < 64) { src = r - 48; sc = RS2_; }
                else             { src = r - 48; sc = SCALE_K; }
                wq[i2] = f2bf(qkv_w[src * 64 + c] * sc);
            } else if (idx < 32848) {
                int r = idx - 32768;
                int src; float sc;
                if (r < 16)      { src = r;      sc = RS2_; }
                else if (r < 32) { src = r;      sc = SCALE_K; }
                else if (r < 48) { src = r + 16; sc = 1.f; }
                else if (r < 64) { src = r - 48; sc = RS2_; }
                else             { src = r - 48; sc = SCALE_K; }
                qb[r] = qkv_b[src] * sc;
            } else if (idx < 135248) {
                int i3 = idx - 32848;
                int ci = i3 / 1600, tv = i3 - ci * 1600;
                pet[tv * 64 + ci] = f2bf(pe[ci * 1600 + tv]);
            } else if (idx < 138448) {
                int i4 = idx - 135248;
                int v = i4 >> 7, r = i4 & 127;
                if (r < 64) dbs[i4] = dbg[r * 25 + v] * rsqrtf(1.f + 1e-5f);
                else        dbs[i4] = dbb[(r - 64) * 25 + v];
            }
        }
        return;
    }
    if (bx == 26) {
        const int n = by;
        #pragma unroll
        for (int it = 0; it < 2; ++it) {
            int item = tid + it * 256;
            int ci = item >> 3, slot = item & 7;
            int t = (slot < 4) ? slot : (56 + slot);
            const float* xp = x + (n * 64 + ci) * TV_ + t * 25;
            float s = 0.f;
            #pragma unroll
            for (int v = 0; v < 25; ++v) s += xp[v];
            Tt[(n * 64 + ci) * 8 + slot] = s;
        }
        return;
    }

    __shared__ ushort smt[64 * 66];      // bf16 transpose tile (stride 66: 2-way write, free read)
    __shared__ float sps[64 * 68];       // f32 [ci][tv] stride-68 (16B-aligned rows)
    const int tv0 = bx * 64;
    const int n = by;

    #pragma unroll
    for (int j = 0; j < 4; ++j) {
        int f4 = tid + j * 256;
        int ci = f4 >> 4, tv4 = f4 & 15;
        float4 v4 = *(const float4*)&x[(n * 64 + ci) * TV_ + tv0 + tv4 * 4];
        *(float4*)&sps[ci * 68 + tv4 * 4] = v4;
        smt[(tv4 * 4 + 0) * 66 + ci] = f2bf(v4.x);
        smt[(tv4 * 4 + 1) * 66 + ci] = f2bf(v4.y);
        smt[(tv4 * 4 + 2) * 66 + ci] = f2bf(v4.z);
        smt[(tv4 * 4 + 3) * 66 + ci] = f2bf(v4.w);
    }
    __syncthreads();

    {
        const int c = tid >> 2, qr = tid & 3;
        float s = 0.f;
        #pragma unroll
        for (int i = 0; i < 16; ++i) s += sps[c * 68 + qr * 16 + i];
        s += __shfl_xor(s, 1);
        s += __shfl_xor(s, 2);
        if (qr == 0) Sp[(n * 25 + bx) * 64 + c] = s;
    }

    #pragma unroll
    for (int j = 0; j < 8; ++j) {
        int chunk = tid + j * 256;
        int tvr = chunk >> 5, p = chunk & 31;
        uint val = *(const uint*)&smt[tvr * 66 + p * 2];
        *(uint*)&rt[(n * TV_ + tv0 + tvr) * 64 + p * 2] = val;
    }
}

// ---------------------------------------------------------------------------
// K1: score kernel per (n,v) — round-10 body (best measured, 43.6us).
// ---------------------------------------------------------------------------
__global__ __launch_bounds__(256, 5) void score_kernel(
    const ushort* __restrict__ rt, const ushort* __restrict__ pet,
    const float* __restrict__ dbs,
    const ushort* __restrict__ wq, const float* __restrict__ qb,
    const float* __restrict__ attn_w, const float* __restrict__ attn_b,
    float* __restrict__ aoc, float* __restrict__ sep)
{
    __shared__ float sm[5856];
    ushort* smu = (ushort*)sm;
    const int MU_ = 1056;
    const int FK2 = 1120, PK2 = 1664, FV2 = 2208, PQ2 = 2752, FQ2 = 3296;
    const int AO2 = 3840;   // 64 rows x stride 20 -> 3840..5119
    const int UN_ = 5312;

    const int b = blockIdx.x;
    const int l = b >> 3;
    const int n = (b & 7) * 8 + l / 25;
    const int v = l % 25;
    const int tid = threadIdx.x;

    const int lane = tid & 63, wave = tid >> 6;
    const int m16 = lane & 15, q = lane >> 4;

    {
        const int part = tid & 7;
        const int ci0 = part * 8;
        float sc8[8], sh8[8];
        *(float4*)&sc8[0] = *(const float4*)&dbs[v * 128 + ci0];
        *(float4*)&sc8[4] = *(const float4*)&dbs[v * 128 + ci0 + 4];
        *(float4*)&sh8[0] = *(const float4*)&dbs[v * 128 + 64 + ci0];
        *(float4*)&sh8[4] = *(const float4*)&dbs[v * 128 + 64 + ci0 + 4];
        #pragma unroll
        for (int j = 0; j < 2; ++j) {
            int t = (tid + j * 256) >> 3;
            uint4 xr = *(const uint4*)&rt[(n * TV_ + t * 25 + v) * 64 + ci0];
            uint4 pr = *(const uint4*)&pet[(t * 25 + v) * 64 + ci0];
            const ushort* xu = (const ushort*)&xr;
            const ushort* pu = (const ushort*)&pr;
            ushort xs[8], ys[8];
            #pragma unroll
            for (int i = 0; i < 8; ++i) {
                float xf = bf2f(xu[i]);
                xs[i] = f2bf(xf * sc8[i] + sh8[i]);
                ys[i] = f2bf(xf + bf2f(pu[i]));
            }
            *(uint4*)&smu[t * 72 + ci0] = *(uint4*)xs;
            *(uint4*)&smu[4608 + t * 72 + ci0] = *(uint4*)ys;
        }
    }
    __syncthreads();

    f32x4 acc[5];
    #pragma unroll
    for (int mt = 0; mt < 5; ++mt) acc[mt] = (f32x4){0.f, 0.f, 0.f, 0.f};
    #pragma unroll
    for (int kt = 0; kt < 2; ++kt) {
        const int koff = kt * 32 + q * 8;
        bf16x8 bx = *(const bf16x8*)&smu[(wave * 16 + m16) * 72 + koff];
        bf16x8 by = *(const bf16x8*)&smu[4608 + (wave * 16 + m16) * 72 + koff];
        #pragma unroll
        for (int mt = 0; mt < 5; ++mt) {
            bf16x8 a = *(const bf16x8*)&wq[(mt * 16 + m16) * 64 + koff];
            acc[mt] = __builtin_amdgcn_mfma_f32_16x16x32_bf16(a, (mt < 3) ? bx : by, acc[mt], 0, 0, 0);
        }
    }
    __syncthreads();

    {
        const int t = wave * 16 + m16;
        #pragma unroll
        for (int r = 0; r < 4; ++r)
            sm[(q * 4 + r) * 66 + t] = acc[0][r] + qb[q * 4 + r];
        const int p0 = (2 * q) * 68 + t, p1 = (2 * q + 1) * 68 + t;
        *(h2f*)&sm[FK2 + p0] = __builtin_amdgcn_cvt_pkrtz(acc[1][0] + qb[16 + 4 * q],     acc[1][1] + qb[16 + 4 * q + 1]);
        *(h2f*)&sm[FK2 + p1] = __builtin_amdgcn_cvt_pkrtz(acc[1][2] + qb[16 + 4 * q + 2], acc[1][3] + qb[16 + 4 * q + 3]);
        *(h2f*)&sm[FV2 + p0] = __builtin_amdgcn_cvt_pkrtz(acc[2][0] + qb[32 + 4 * q],     acc[2][1] + qb[32 + 4 * q + 1]);
        *(h2f*)&sm[FV2 + p1] = __builtin_amdgcn_cvt_pkrtz(acc[2][2] + qb[32 + 4 * q + 2], acc[2][3] + qb[32 + 4 * q + 3]);
        *(h2f*)&sm[PQ2 + p0] = __builtin_amdgcn_cvt_pkrtz(acc[3][0] + qb[48 + 4 * q],     acc[3][1] + qb[48 + 4 * q + 1]);
        *(h2f*)&sm[PQ2 + p1] = __builtin_amdgcn_cvt_pkrtz(acc[3][2] + qb[48 + 4 * q + 2], acc[3][3] + qb[48 + 4 * q + 3]);
        *(h2f*)&sm[PK2 + p0] = __builtin_amdgcn_cvt_pkrtz(acc[4][0] + qb[64 + 4 * q],     acc[4][1] + qb[64 + 4 * q + 1]);
        *(h2f*)&sm[PK2 + p1] = __builtin_amdgcn_cvt_pkrtz(acc[4][2] + qb[64 + 4 * q + 2], acc[4][3] + qb[64 + 4 * q + 3]);
    }
    __syncthreads();

    if (tid < 64) {
        int ch = tid & 15, qq = tid >> 4;
        float s = 0.f;
        #pragma unroll
        for (int t = 0; t < 16; ++t) s += sm[ch * 66 + qq * 16 + t];
        sm[MU_ + qq * 16 + ch] = s;
    }
    __syncthreads();
    if (tid < 16) {
        float mval = (sm[MU_ + tid] + sm[MU_ + 16 + tid] + sm[MU_ + 32 + tid] + sm[MU_ + 48 + tid]) * (1.f / 64.f);
        sm[MU_ + tid] = mval;
    }
    __syncthreads();

    #pragma unroll
    for (int e = 0; e < 2; ++e) {
        int idx = tid * 2 + e;
        int s = idx >> 3, h = idx & 7;
        float a = sm[(2 * h) * 66 + s] - sm[MU_ + 2 * h];
        float c = sm[(2 * h + 1) * 66 + s] - sm[MU_ + 2 * h + 1];
        *(h2f*)&sm[FQ2 + h * 68 + s] = __builtin_amdgcn_cvt_pkrtz(a, c);
    }
    {
        const int h = tid & 7, tt = tid >> 3;   // tt 0..31
        h2f mp = __builtin_amdgcn_cvt_pkrtz(sm[MU_ + 2 * h], sm[MU_ + 2 * h + 1]);
        sm[UN_ + h * 68 + tt]      = dot2f(mp, *(const h2f*)&sm[FK2 + h * 68 + tt], 0.f);
        sm[UN_ + h * 68 + tt + 32] = dot2f(mp, *(const h2f*)&sm[FK2 + h * 68 + tt + 32], 0.f);
    }
    __syncthreads();

    {
        const int h = tid & 7, sp = tid >> 3;   // sp 0..31 -> s = 2sp, 2sp+1
        const int hb = h * 68;
        F2H fqp, pqp;
        fqp.f = *(const float2*)&sm[FQ2 + hb + 2 * sp];
        pqp.f = *(const float2*)&sm[PQ2 + hb + 2 * sp];
        const h2f fq0 = fqp.h[0], fq1 = fqp.h[1];
        const h2f pq0 = pqp.h[0], pq1 = pqp.h[1];
        float ao00 = 0.f, ao01 = 0.f, ao10 = 0.f, ao11 = 0.f;
        #pragma unroll 2
        for (int t4 = 0; t4 < 16; ++t4) {
            F4H fk4, pk4, fv4;
            fk4.f = *(const float4*)&sm[FK2 + hb + 4 * t4];
            pk4.f = *(const float4*)&sm[PK2 + hb + 4 * t4];
            fv4.f = *(const float4*)&sm[FV2 + hb + 4 * t4];
            float4 un4 = *(const float4*)&sm[UN_ + hb + 4 * t4];
            const float* unp = (const float*)&un4;
            #pragma unroll
            for (int j = 0; j < 4; ++j) {
                float un = unp[j];
                float fva = (float)fv4.h[j].x, fvb = (float)fv4.h[j].y;
                float lp0 = dot2f(pq0, pk4.h[j], 0.f);
                float a10 = dot2f(fq0, fk4.h[j], lp0);
                float w0 = tanh4(a10) + tanh4(un + lp0);
                ao00 = __builtin_fmaf(w0, fva, ao00);
                ao01 = __builtin_fmaf(w0, fvb, ao01);
                float lp1 = dot2f(pq1, pk4.h[j], 0.f);
                float a11 = dot2f(fq1, fk4.h[j], lp1);
                float w1 = tanh4(a11) + tanh4(un + lp1);
                ao10 = __builtin_fmaf(w1, fva, ao10);
                ao11 = __builtin_fmaf(w1, fvb, ao11);
            }
        }
        *(float2*)&sm[AO2 + (2 * sp) * 20 + 2 * h]     = make_float2(ao00, ao01);
        *(float2*)&sm[AO2 + (2 * sp + 1) * 20 + 2 * h] = make_float2(ao10, ao11);
    }
    __syncthreads();

    const int t = tid & 63, oq = tid >> 6;
    float aorow[16];
    #pragma unroll
    for (int i = 0; i < 4; ++i)
        *(float4*)&aorow[i * 4] = *(const float4*)&sm[AO2 + t * 20 + i * 4];
    float* aop = aoc + (n * 25 + v) * 1024;
    #pragma unroll
    for (int j = 0; j < 4; ++j) {
        int o = oq * 4 + j;
        float acc4 = attn_b[o];
        #pragma unroll
        for (int c = 0; c < 16; ++c) acc4 += attn_w[o * 16 + c] * aorow[c];
        aop[o * 64 + t] = acc4;
        float ssum = acc4;
        #pragma unroll
        for (int off = 32; off >= 1; off >>= 1) ssum += __shfl_down(ssum, off, 64);
        if ((tid & 63) == 0) sep[(n * 25 + v) * 16 + o] = ssum;
    }
}

// ---------------------------------------------------------------------------
// G1: gate kernel — one block per n. (unchanged)
// ---------------------------------------------------------------------------
__global__ __launch_bounds__(256) void gate_kernel(
    const float* __restrict__ Sp, const float* __restrict__ Tt,
    const float* __restrict__ sep, const ushort* __restrict__ wb,
    const float* __restrict__ tcn_b, const float* __restrict__ tg,
    const float* __restrict__ tb,
    const float* __restrict__ fc1w, const float* __restrict__ fc1b,
    const float* __restrict__ fc2w, const float* __restrict__ fc2b,
    float* __restrict__ gateG)
{
    __shared__ float U[576];
    __shared__ float gp[432];
    __shared__ float SS[64], sepS[16], seL[64], hid[32];
    const int n = blockIdx.x;
    const int tid = threadIdx.x;
    const float rsbn = rsqrtf(1.f + 1e-5f);

    {
        const int c = tid >> 2, qr = tid & 3;
        float s = 0.f;
        #pragma unroll 1
        for (int j = qr; j < 25; j += 4) s += Sp[(n * 25 + j) * 64 + c];
        s += __shfl_xor(s, 1);
        s += __shfl_xor(s, 2);
        if (qr == 0) SS[c] = s;
    }
    if (tid < 64) {
        const int o = tid >> 2, qr = tid & 3;
        float s = 0.f;
        #pragma unroll 1
        for (int j = qr; j < 25; j += 4) s += sep[(n * 25 + j) * 16 + o];
        s += __shfl_xor(s, 1);
        s += __shfl_xor(s, 2);
        if (qr == 0) sepS[o] = s;
    }
    __syncthreads();
    if (tid < 64) {
        float S = SS[tid];
        float T[8];
        #pragma unroll
        for (int j = 0; j < 8; ++j) T[j] = Tt[(n * 64 + tid) * 8 + j];
        U[tid * 9 + 0] = S - (T[4] + T[5] + T[6] + T[7]);
        U[tid * 9 + 1] = S - (T[5] + T[6] + T[7]);
        U[tid * 9 + 2] = S - (T[6] + T[7]);
        U[tid * 9 + 3] = S - T[7];
        U[tid * 9 + 4] = S;
        U[tid * 9 + 5] = S - T[0];
        U[tid * 9 + 6] = S - (T[0] + T[1]);
        U[tid * 9 + 7] = S - (T[0] + T[1] + T[2]);
        U[tid * 9 + 8] = S - (T[0] + T[1] + T[2] + T[3]);
    }
    __syncthreads();
    if (tid < 432) {
        int oc = tid / 9, kt = tid - oc * 9;
        float cs = 0.f;
        #pragma unroll
        for (int cb = 0; cb < 8; ++cb) {
            bf16x8 w8 = *(const bf16x8*)&wb[oc * 576 + kt * 64 + cb * 8];
            #pragma unroll
            for (int i = 0; i < 8; ++i)
                cs += bf2f((ushort)w8[i]) * U[(cb * 8 + i) * 9 + kt];
        }
        gp[tid] = cs;
    }
    __syncthreads();
    if (tid < 64) {
        if (tid < 48) {
            float cs = 0.f;
            #pragma unroll
            for (int kt = 0; kt < 9; ++kt) cs += gp[tid * 9 + kt];
            float a = tg[tid] * rsbn;
            float cb_ = tcn_b[tid] * a + tb[tid];
            seL[tid] = (a * cs + 1600.f * cb_ + SS[tid]) * (1.f / 1600.f);
        } else {
            seL[tid] = (sepS[tid - 48] + SS[tid]) * (1.f / 1600.f);
        }
    }
    __syncthreads();
    if (tid < 32) {
        float a = fc1b[tid];
        #pragma unroll
        for (int c = 0; c < 64; ++c) a += fc1w[tid * 64 + c] * seL[c];
        hid[tid] = fmaxf(a, 0.f);
    }
    __syncthreads();
    if (tid < 64) {
        float g = fc2b[tid];
        #pragma unroll
        for (int j = 0; j < 32; ++j) g += fc2w[tid * 32 + j] * hid[j];
        gateG[n * 64 + tid] = 1.f / (1.f + __expf(-g));
    }
}

// ---------------------------------------------------------------------------
// K2: tcn MFMA + merged final phase. Grid 256 -> 512 blocks (n x 8 t-tiles):
// old grid was exactly 1 block/CU (8 waves, 25% occupancy, all latency
// exposed). Now LDS 31KB -> 2 blocks/CU. Conv mapping: xsl row 0 = tv
// t0*25-100; out posg = tile*200 + p; read row = p + kt*25.
// ---------------------------------------------------------------------------
__global__ __launch_bounds__(512, 2) void tcn_mfma_kernel(
    const ushort* __restrict__ rt, const float* __restrict__ x,
    const ushort* __restrict__ wb,
    const float* __restrict__ tcn_b, const float* __restrict__ tg,
    const float* __restrict__ tb,
    const float* __restrict__ gateG, const float* __restrict__ aoc,
    const float* __restrict__ bng, const float* __restrict__ bnb,
    float* __restrict__ out)
{
    __shared__ ushort xsl[408 * 38];     // 31,008 B
    __shared__ float gateL[64];

    const int b = blockIdx.x;
    const int n = b >> 3, tile = b & 7;
    const int tid = threadIdx.x;
    const float rsbn = rsqrtf(1.f + 1e-5f);
    const int tvbase = tile * 200 - 100;

    if (tid < 64) gateL[tid] = gateG[n * 64 + tid];

    const int lane = tid & 63, wave = tid >> 6;
    const int m16 = lane & 15, q = lane >> 4;

    f32x4 acc[2][3];
    #pragma unroll
    for (int rr = 0; rr < 2; ++rr)
        #pragma unroll
        for (int mt = 0; mt < 3; ++mt)
            acc[rr][mt] = (f32x4){0.f, 0.f, 0.f, 0.f};

    #pragma unroll 1
    for (int hf = 0; hf < 2; ++hf) {
        if (hf) __syncthreads();         // all reads of previous half done
        for (int idx = tid; idx < 1632; idx += 512) {   // 408 rows x 4 parts
            int r = idx >> 2, part = idx & 3;
            int tv = tvbase + r;
            uint4 val = make_uint4(0u, 0u, 0u, 0u);
            if (tv >= 0 && tv < TV_) val = *(const uint4*)&rt[(n * TV_ + tv) * 64 + hf * 32 + part * 8];
            *(uint4*)&xsl[r * 38 + part * 8] = val;
        }
        __syncthreads();
        #pragma unroll 1
        for (int kt = 0; kt < 9; ++kt) {
            const int ktile = kt * 2 + hf;
            bf16x8 afr[3];
            #pragma unroll
            for (int mt = 0; mt < 3; ++mt)
                afr[mt] = *(const bf16x8*)&wb[(mt * 16 + m16) * 576 + ktile * 32 + q * 8];
            #pragma unroll
            for (int rr = 0; rr < 2; ++rr) {
                int w = wave + rr * 8;
                if (w <= 12) {
                    int p = w * 16 + m16;                 // p <= 207; row <= 407 in-bounds
                    bf16x8 bfr = *(const bf16x8*)&xsl[(p + kt * 25) * 38 + q * 8];
                    #pragma unroll
                    for (int mt = 0; mt < 3; ++mt)
                        acc[rr][mt] = __builtin_amdgcn_mfma_f32_16x16x32_bf16(afr[mt], bfr, acc[rr][mt], 0, 0, 0);
                }
            }
        }
    }

    #pragma unroll
    for (int mt = 0; mt < 3; ++mt) {
        #pragma unroll
        for (int r = 0; r < 4; ++r) {
            int oc = mt * 16 + q * 4 + r;
            float a = tg[oc] * rsbn;
            float cb_ = tcn_b[oc] * a + tb[oc];
            float mm = (1.f + gateL[oc]) * (bng[oc] * rsbn);
            float bb = bnb[oc];
            #pragma unroll
            for (int rr = 0; rr < 2; ++rr) {
                int w = wave + rr * 8;
                if (w <= 12) {
                    int p = w * 16 + m16;
                    if (p < 200) {
                        int posg = tile * 200 + p;
                        float val = acc[rr][mt][r] + cb_ + x[(n * 64 + oc) * TV_ + posg];
                        out[(n * 64 + oc) * TV_ + posg] = fmaxf(val * mm + bb, 0.f);
                    }
                }
            }
        }
    }

    // merged final phase: c>=48, this block's posg range tile*200..tile*200+199
    __syncthreads();                 // xsl dead -> reuse as ts[v][o][lt], stride 132
    float* ts = (float*)xsl;         // 25*132 = 3300 floats = 13.2KB <= 31KB
    for (int task = tid; task < 800; task += 512) {   // 25 v x 16 o x 2 f
        int v = task >> 5;
        int r = task & 31;
        int o = r >> 1, f = r & 1;
        float4 d = *(const float4*)&aoc[(n * 25 + v) * 1024 + o * 64 + tile * 8 + f * 4];
        *(float4*)&ts[v * 132 + o * 8 + f * 4] = d;
    }
    __syncthreads();
    for (int p4 = tid; p4 < 800; p4 += 512) {   // 16 o x 50 float4
        int o = p4 / 50, r4 = p4 - o * 50;
        int base4 = (n * 64 + 48 + o) * 400 + tile * 50 + r4;
        float4 xr = ((const float4*)x)[base4];
        float4 val;
        #pragma unroll
        for (int e = 0; e < 4; ++e) {
            int pos = r4 * 4 + e;                // 0..199 within tile
            int lt = pos / 25, v = pos - lt * 25;
            ((float*)&val)[e] = ts[v * 132 + o * 8 + lt];
        }
        float mm = (1.f + gateL[48 + o]) * (bng[48 + o] * rsbn);
        float bb = bnb[48 + o];
        val.x = fmaxf((val.x + xr.x) * mm + bb, 0.f);
        val.y = fmaxf((val.y + xr.y) * mm + bb, 0.f);
        val.z = fmaxf((val.z + xr.z) * mm + bb, 0.f);
        val.w = fmaxf((val.w + xr.w) * mm + bb, 0.f);
        ((float4*)out)[base4] = val;
    }
}

extern "C" void kernel_launch(void* const* d_in, const int* in_sizes, int n_in,
                              void* d_out, int out_size, void* d_ws, size_t ws_size,
                              hipStream_t stream) {
    const float* x     = (const float*)d_in[0];
    const float* pe    = (const float*)d_in[1];
    const float* dbg   = (const float*)d_in[2];
    const float* dbb   = (const float*)d_in[3];
    const float* qkvw  = (const float*)d_in[4];
    const float* qkvb  = (const float*)d_in[5];
    const float* attnw = (const float*)d_in[6];
    const float* attnb = (const float*)d_in[7];
    const float* tcnw  = (const float*)d_in[8];
    const float* tcnb  = (const float*)d_in[9];
    const float* tcng  = (const float*)d_in[10];
    const float* tcnbb = (const float*)d_in[11];
    const float* fc1w  = (const float*)d_in[12];
    const float* fc1b  = (const float*)d_in[13];
    const float* fc2w  = (const float*)d_in[14];
    const float* fc2b  = (const float*)d_in[15];
    const float* bng   = (const float*)d_in[16];
    const float* bnb   = (const float*)d_in[17];

    float* out  = (float*)d_out;
    float* Sp   = (float*)d_ws;                      // 64*25*64 = 102400 f
    float* sep  = Sp + 102400;                       // 64*25*16 = 25600 f
    float* Tt   = sep + 25600;                       // 32768 f
    float* qb   = Tt + 32768;                        // 96 f
    float* aoc  = qb + 96;                           // 1,638,400 f
    ushort* wb  = (ushort*)(aoc + 1638400);          // 27648 u16
    ushort* wq  = wb + 27648;                        // 5120 u16
    ushort* pet = wq + 5120;                         // 102,400 u16
    ushort* rt  = pet + 102400;                      // 6,553,600 u16
    float* gateG = (float*)(rt + 6553600);           // 4096 f
    float* dbs  = gateG + 4096;                      // 3200 f

    t1_kernel<<<dim3(27, 64), dim3(256), 0, stream>>>(
        x, pe, tcnw, tcng, qkvw, qkvb, dbg, dbb, rt, Sp, Tt, wb, wq, qb, pet, dbs);
    score_kernel<<<dim3(1600), dim3(256), 0, stream>>>(rt, pet, dbs, wq, qb, attnw, attnb, aoc, sep);
    gate_kernel<<<dim3(64), dim3(256), 0, stream>>>(
        Sp, Tt, sep, wb, tcnb, tcng, tcnbb, fc1w, fc1b, fc2w, fc2b, gateG);
    tcn_mfma_kernel<<<dim3(512), dim3(512), 0, stream>>>(
        rt, x, wb, tcnb, tcng, tcnbb, gateG, aoc, bng, bnb, out);
}

// Round 12
// 187.493 us; speedup vs baseline: 1.0920x; 1.0920x over previous
//
#include <hip/hip_runtime.h>
#include <hip/hip_bf16.h>
#include <math.h>

#define TV_ 1600
#define SCALE_K 2.885390081777927f
#define RS2_ 0.70710678118654752f

typedef __attribute__((ext_vector_type(8))) short bf16x8;
typedef __attribute__((ext_vector_type(4))) float f32x4;
typedef __attribute__((ext_vector_type(2))) __fp16 h2f;

union F4H { float4 f; h2f h[4]; };
union F2H { float2 f; h2f h[2]; };

// clamp-free tanh on pre-scaled input y = x * 2/ln2:
// tanh(x) = 1 - 2/(2^y + 1); exp2(+big)=inf -> rcp=0 -> 1; exp2(-big)=0 -> rcp(1)=1 -> -1
__device__ __forceinline__ float tanh4(float y) {
    float e = __builtin_amdgcn_exp2f(y);
    float r = __builtin_amdgcn_rcpf(e + 1.f);
    return __builtin_fmaf(-2.f, r, 1.f);
}

__device__ __forceinline__ float dot2f(h2f a, h2f b, float c) {
    return __builtin_amdgcn_fdot2(a, b, c, false);
}

__device__ __forceinline__ ushort f2bf(float f) {
    __hip_bfloat16 h = __float2bfloat16(f);
    return *(ushort*)&h;
}
__device__ __forceinline__ float bf2f(ushort u) {
    uint w = ((uint)u) << 16;
    return __uint_as_float(w);
}

// ---------------------------------------------------------------------------
// T1: bx<25 transpose -> rt + Sp partials via LDS column-reduce; bx==25 prep;
// bx==26 edge sums Tt. x loads vectorized to float4.
// ---------------------------------------------------------------------------
__global__ __launch_bounds__(256) void t1_kernel(
    const float* __restrict__ x, const float* __restrict__ pe,
    const float* __restrict__ tcn_w, const float* __restrict__ tg,
    const float* __restrict__ qkv_w, const float* __restrict__ qkv_b,
    const float* __restrict__ dbg, const float* __restrict__ dbb,
    ushort* __restrict__ rt, float* __restrict__ Sp, float* __restrict__ Tt,
    ushort* __restrict__ wb, ushort* __restrict__ wq, float* __restrict__ qb,
    ushort* __restrict__ pet, float* __restrict__ dbs)
{
    const int tid = threadIdx.x;
    const int bx = blockIdx.x, by = blockIdx.y;

    if (bx == 25) {
        #pragma unroll 1
        for (int j = 0; j < 9; ++j) {
            int idx = by * 256 + tid + j * 16384;
            if (idx < 27648) {
                int oc = idx / 576, kk = idx - oc * 576;
                int kt = kk >> 6, ci = kk & 63;
                float a = tg[oc] * rsqrtf(1.f + 1e-5f);
                wb[idx] = f2bf(tcn_w[(oc * 64 + ci) * 9 + kt] * a);
            } else if (idx < 32768) {
                int i2 = idx - 27648;
                int r = i2 >> 6, c = i2 & 63;
                int src; float sc;
                if (r < 16)      { src = r;      sc = RS2_; }
                else if (r < 32) { src = r;      sc = SCALE_K; }
                else if (r < 48) { src = r + 16; sc = 1.f; }
                else if (r < 64) { src = r - 48; sc = RS2_; }
                else             { src = r - 48; sc = SCALE_K; }
                wq[i2] = f2bf(qkv_w[src * 64 + c] * sc);
            } else if (idx < 32848) {
                int r = idx - 32768;
                int src; float sc;
                if (r < 16)      { src = r;      sc = RS2_; }
                else if (r < 32) { src = r;      sc = SCALE_K; }
                else if (r < 48) { src = r + 16; sc = 1.f; }
                else if (r < 64) { src = r - 48; sc = RS2_; }
                else             { src = r - 48; sc = SCALE_K; }
                qb[r] = qkv_b[src] * sc;
            } else if (idx < 135248) {
                int i3 = idx - 32848;
                int ci = i3 / 1600, tv = i3 - ci * 1600;
                pet[tv * 64 + ci] = f2bf(pe[ci * 1600 + tv]);
            } else if (idx < 138448) {
                int i4 = idx - 135248;
                int v = i4 >> 7, r = i4 & 127;
                if (r < 64) dbs[i4] = dbg[r * 25 + v] * rsqrtf(1.f + 1e-5f);
                else        dbs[i4] = dbb[(r - 64) * 25 + v];
            }
        }
        return;
    }
    if (bx == 26) {
        const int n = by;
        #pragma unroll
        for (int it = 0; it < 2; ++it) {
            int item = tid + it * 256;
            int ci = item >> 3, slot = item & 7;
            int t = (slot < 4) ? slot : (56 + slot);
            const float* xp = x + (n * 64 + ci) * TV_ + t * 25;
            float s = 0.f;
            #pragma unroll
            for (int v = 0; v < 25; ++v) s += xp[v];
            Tt[(n * 64 + ci) * 8 + slot] = s;
        }
        return;
    }

    __shared__ ushort smt[64 * 66];      // bf16 transpose tile (stride 66: 2-way write, free read)
    __shared__ float sps[64 * 68];       // f32 [ci][tv] stride-68 (16B-aligned rows)
    const int tv0 = bx * 64;
    const int n = by;

    #pragma unroll
    for (int j = 0; j < 4; ++j) {
        int f4 = tid + j * 256;
        int ci = f4 >> 4, tv4 = f4 & 15;
        float4 v4 = *(const float4*)&x[(n * 64 + ci) * TV_ + tv0 + tv4 * 4];
        *(float4*)&sps[ci * 68 + tv4 * 4] = v4;
        smt[(tv4 * 4 + 0) * 66 + ci] = f2bf(v4.x);
        smt[(tv4 * 4 + 1) * 66 + ci] = f2bf(v4.y);
        smt[(tv4 * 4 + 2) * 66 + ci] = f2bf(v4.z);
        smt[(tv4 * 4 + 3) * 66 + ci] = f2bf(v4.w);
    }
    __syncthreads();

    {
        const int c = tid >> 2, qr = tid & 3;
        float s = 0.f;
        #pragma unroll
        for (int i = 0; i < 16; ++i) s += sps[c * 68 + qr * 16 + i];
        s += __shfl_xor(s, 1);
        s += __shfl_xor(s, 2);
        if (qr == 0) Sp[(n * 25 + bx) * 64 + c] = s;
    }

    #pragma unroll
    for (int j = 0; j < 8; ++j) {
        int chunk = tid + j * 256;
        int tvr = chunk >> 5, p = chunk & 31;
        uint val = *(const uint*)&smt[tvr * 66 + p * 2];
        *(uint*)&rt[(n * TV_ + tv0 + tvr) * 64 + p * 2] = val;
    }
}

// ---------------------------------------------------------------------------
// K1: score kernel per (n,v) — round-10 body (best measured, 43.6us).
// ---------------------------------------------------------------------------
__global__ __launch_bounds__(256, 5) void score_kernel(
    const ushort* __restrict__ rt, const ushort* __restrict__ pet,
    const float* __restrict__ dbs,
    const ushort* __restrict__ wq, const float* __restrict__ qb,
    const float* __restrict__ attn_w, const float* __restrict__ attn_b,
    float* __restrict__ aoc, float* __restrict__ sep)
{
    __shared__ float sm[5856];
    ushort* smu = (ushort*)sm;
    const int MU_ = 1056;
    const int FK2 = 1120, PK2 = 1664, FV2 = 2208, PQ2 = 2752, FQ2 = 3296;
    const int AO2 = 3840;   // 64 rows x stride 20 -> 3840..5119
    const int UN_ = 5312;

    const int b = blockIdx.x;
    const int l = b >> 3;
    const int n = (b & 7) * 8 + l / 25;
    const int v = l % 25;
    const int tid = threadIdx.x;

    const int lane = tid & 63, wave = tid >> 6;
    const int m16 = lane & 15, q = lane >> 4;

    {
        const int part = tid & 7;
        const int ci0 = part * 8;
        float sc8[8], sh8[8];
        *(float4*)&sc8[0] = *(const float4*)&dbs[v * 128 + ci0];
        *(float4*)&sc8[4] = *(const float4*)&dbs[v * 128 + ci0 + 4];
        *(float4*)&sh8[0] = *(const float4*)&dbs[v * 128 + 64 + ci0];
        *(float4*)&sh8[4] = *(const float4*)&dbs[v * 128 + 64 + ci0 + 4];
        #pragma unroll
        for (int j = 0; j < 2; ++j) {
            int t = (tid + j * 256) >> 3;
            uint4 xr = *(const uint4*)&rt[(n * TV_ + t * 25 + v) * 64 + ci0];
            uint4 pr = *(const uint4*)&pet[(t * 25 + v) * 64 + ci0];
            const ushort* xu = (const ushort*)&xr;
            const ushort* pu = (const ushort*)&pr;
            ushort xs[8], ys[8];
            #pragma unroll
            for (int i = 0; i < 8; ++i) {
                float xf = bf2f(xu[i]);
                xs[i] = f2bf(xf * sc8[i] + sh8[i]);
                ys[i] = f2bf(xf + bf2f(pu[i]));
            }
            *(uint4*)&smu[t * 72 + ci0] = *(uint4*)xs;
            *(uint4*)&smu[4608 + t * 72 + ci0] = *(uint4*)ys;
        }
    }
    __syncthreads();

    f32x4 acc[5];
    #pragma unroll
    for (int mt = 0; mt < 5; ++mt) acc[mt] = (f32x4){0.f, 0.f, 0.f, 0.f};
    #pragma unroll
    for (int kt = 0; kt < 2; ++kt) {
        const int koff = kt * 32 + q * 8;
        bf16x8 bx = *(const bf16x8*)&smu[(wave * 16 + m16) * 72 + koff];
        bf16x8 by = *(const bf16x8*)&smu[4608 + (wave * 16 + m16) * 72 + koff];
        #pragma unroll
        for (int mt = 0; mt < 5; ++mt) {
            bf16x8 a = *(const bf16x8*)&wq[(mt * 16 + m16) * 64 + koff];
            acc[mt] = __builtin_amdgcn_mfma_f32_16x16x32_bf16(a, (mt < 3) ? bx : by, acc[mt], 0, 0, 0);
        }
    }
    __syncthreads();

    {
        const int t = wave * 16 + m16;
        #pragma unroll
        for (int r = 0; r < 4; ++r)
            sm[(q * 4 + r) * 66 + t] = acc[0][r] + qb[q * 4 + r];
        const int p0 = (2 * q) * 68 + t, p1 = (2 * q + 1) * 68 + t;
        *(h2f*)&sm[FK2 + p0] = __builtin_amdgcn_cvt_pkrtz(acc[1][0] + qb[16 + 4 * q],     acc[1][1] + qb[16 + 4 * q + 1]);
        *(h2f*)&sm[FK2 + p1] = __builtin_amdgcn_cvt_pkrtz(acc[1][2] + qb[16 + 4 * q + 2], acc[1][3] + qb[16 + 4 * q + 3]);
        *(h2f*)&sm[FV2 + p0] = __builtin_amdgcn_cvt_pkrtz(acc[2][0] + qb[32 + 4 * q],     acc[2][1] + qb[32 + 4 * q + 1]);
        *(h2f*)&sm[FV2 + p1] = __builtin_amdgcn_cvt_pkrtz(acc[2][2] + qb[32 + 4 * q + 2], acc[2][3] + qb[32 + 4 * q + 3]);
        *(h2f*)&sm[PQ2 + p0] = __builtin_amdgcn_cvt_pkrtz(acc[3][0] + qb[48 + 4 * q],     acc[3][1] + qb[48 + 4 * q + 1]);
        *(h2f*)&sm[PQ2 + p1] = __builtin_amdgcn_cvt_pkrtz(acc[3][2] + qb[48 + 4 * q + 2], acc[3][3] + qb[48 + 4 * q + 3]);
        *(h2f*)&sm[PK2 + p0] = __builtin_amdgcn_cvt_pkrtz(acc[4][0] + qb[64 + 4 * q],     acc[4][1] + qb[64 + 4 * q + 1]);
        *(h2f*)&sm[PK2 + p1] = __builtin_amdgcn_cvt_pkrtz(acc[4][2] + qb[64 + 4 * q + 2], acc[4][3] + qb[64 + 4 * q + 3]);
    }
    __syncthreads();

    if (tid < 64) {
        int ch = tid & 15, qq = tid >> 4;
        float s = 0.f;
        #pragma unroll
        for (int t = 0; t < 16; ++t) s += sm[ch * 66 + qq * 16 + t];
        sm[MU_ + qq * 16 + ch] = s;
    }
    __syncthreads();
    if (tid < 16) {
        float mval = (sm[MU_ + tid] + sm[MU_ + 16 + tid] + sm[MU_ + 32 + tid] + sm[MU_ + 48 + tid]) * (1.f / 64.f);
        sm[MU_ + tid] = mval;
    }
    __syncthreads();

    #pragma unroll
    for (int e = 0; e < 2; ++e) {
        int idx = tid * 2 + e;
        int s = idx >> 3, h = idx & 7;
        float a = sm[(2 * h) * 66 + s] - sm[MU_ + 2 * h];
        float c = sm[(2 * h + 1) * 66 + s] - sm[MU_ + 2 * h + 1];
        *(h2f*)&sm[FQ2 + h * 68 + s] = __builtin_amdgcn_cvt_pkrtz(a, c);
    }
    {
        const int h = tid & 7, tt = tid >> 3;   // tt 0..31
        h2f mp = __builtin_amdgcn_cvt_pkrtz(sm[MU_ + 2 * h], sm[MU_ + 2 * h + 1]);
        sm[UN_ + h * 68 + tt]      = dot2f(mp, *(const h2f*)&sm[FK2 + h * 68 + tt], 0.f);
        sm[UN_ + h * 68 + tt + 32] = dot2f(mp, *(const h2f*)&sm[FK2 + h * 68 + tt + 32], 0.f);
    }
    __syncthreads();

    {
        const int h = tid & 7, sp = tid >> 3;   // sp 0..31 -> s = 2sp, 2sp+1
        const int hb = h * 68;
        F2H fqp, pqp;
        fqp.f = *(const float2*)&sm[FQ2 + hb + 2 * sp];
        pqp.f = *(const float2*)&sm[PQ2 + hb + 2 * sp];
        const h2f fq0 = fqp.h[0], fq1 = fqp.h[1];
        const h2f pq0 = pqp.h[0], pq1 = pqp.h[1];
        float ao00 = 0.f, ao01 = 0.f, ao10 = 0.f, ao11 = 0.f;
        #pragma unroll 2
        for (int t4 = 0; t4 < 16; ++t4) {
            F4H fk4, pk4, fv4;
            fk4.f = *(const float4*)&sm[FK2 + hb + 4 * t4];
            pk4.f = *(const float4*)&sm[PK2 + hb + 4 * t4];
            fv4.f = *(const float4*)&sm[FV2 + hb + 4 * t4];
            float4 un4 = *(const float4*)&sm[UN_ + hb + 4 * t4];
            const float* unp = (const float*)&un4;
            #pragma unroll
            for (int j = 0; j < 4; ++j) {
                float un = unp[j];
                float fva = (float)fv4.h[j].x, fvb = (float)fv4.h[j].y;
                float lp0 = dot2f(pq0, pk4.h[j], 0.f);
                float a10 = dot2f(fq0, fk4.h[j], lp0);
                float w0 = tanh4(a10) + tanh4(un + lp0);
                ao00 = __builtin_fmaf(w0, fva, ao00);
                ao01 = __builtin_fmaf(w0, fvb, ao01);
                float lp1 = dot2f(pq1, pk4.h[j], 0.f);
                float a11 = dot2f(fq1, fk4.h[j], lp1);
                float w1 = tanh4(a11) + tanh4(un + lp1);
                ao10 = __builtin_fmaf(w1, fva, ao10);
                ao11 = __builtin_fmaf(w1, fvb, ao11);
            }
        }
        *(float2*)&sm[AO2 + (2 * sp) * 20 + 2 * h]     = make_float2(ao00, ao01);
        *(float2*)&sm[AO2 + (2 * sp + 1) * 20 + 2 * h] = make_float2(ao10, ao11);
    }
    __syncthreads();

    const int t = tid & 63, oq = tid >> 6;
    float aorow[16];
    #pragma unroll
    for (int i = 0; i < 4; ++i)
        *(float4*)&aorow[i * 4] = *(const float4*)&sm[AO2 + t * 20 + i * 4];
    float* aop = aoc + (n * 25 + v) * 1024;
    #pragma unroll
    for (int j = 0; j < 4; ++j) {
        int o = oq * 4 + j;
        float acc4 = attn_b[o];
        #pragma unroll
        for (int c = 0; c < 16; ++c) acc4 += attn_w[o * 16 + c] * aorow[c];
        aop[o * 64 + t] = acc4;
        float ssum = acc4;
        #pragma unroll
        for (int off = 32; off >= 1; off >>= 1) ssum += __shfl_down(ssum, off, 64);
        if ((tid & 63) == 0) sep[(n * 25 + v) * 16 + o] = ssum;
    }
}

// ---------------------------------------------------------------------------
// G1: gate kernel — one block per n. (unchanged)
// ---------------------------------------------------------------------------
__global__ __launch_bounds__(256) void gate_kernel(
    const float* __restrict__ Sp, const float* __restrict__ Tt,
    const float* __restrict__ sep, const ushort* __restrict__ wb,
    const float* __restrict__ tcn_b, const float* __restrict__ tg,
    const float* __restrict__ tb,
    const float* __restrict__ fc1w, const float* __restrict__ fc1b,
    const float* __restrict__ fc2w, const float* __restrict__ fc2b,
    float* __restrict__ gateG)
{
    __shared__ float U[576];
    __shared__ float gp[432];
    __shared__ float SS[64], sepS[16], seL[64], hid[32];
    const int n = blockIdx.x;
    const int tid = threadIdx.x;
    const float rsbn = rsqrtf(1.f + 1e-5f);

    {
        const int c = tid >> 2, qr = tid & 3;
        float s = 0.f;
        #pragma unroll 1
        for (int j = qr; j < 25; j += 4) s += Sp[(n * 25 + j) * 64 + c];
        s += __shfl_xor(s, 1);
        s += __shfl_xor(s, 2);
        if (qr == 0) SS[c] = s;
    }
    if (tid < 64) {
        const int o = tid >> 2, qr = tid & 3;
        float s = 0.f;
        #pragma unroll 1
        for (int j = qr; j < 25; j += 4) s += sep[(n * 25 + j) * 16 + o];
        s += __shfl_xor(s, 1);
        s += __shfl_xor(s, 2);
        if (qr == 0) sepS[o] = s;
    }
    __syncthreads();
    if (tid < 64) {
        float S = SS[tid];
        float T[8];
        #pragma unroll
        for (int j = 0; j < 8; ++j) T[j] = Tt[(n * 64 + tid) * 8 + j];
        U[tid * 9 + 0] = S - (T[4] + T[5] + T[6] + T[7]);
        U[tid * 9 + 1] = S - (T[5] + T[6] + T[7]);
        U[tid * 9 + 2] = S - (T[6] + T[7]);
        U[tid * 9 + 3] = S - T[7];
        U[tid * 9 + 4] = S;
        U[tid * 9 + 5] = S - T[0];
        U[tid * 9 + 6] = S - (T[0] + T[1]);
        U[tid * 9 + 7] = S - (T[0] + T[1] + T[2]);
        U[tid * 9 + 8] = S - (T[0] + T[1] + T[2] + T[3]);
    }
    __syncthreads();
    if (tid < 432) {
        int oc = tid / 9, kt = tid - oc * 9;
        float cs = 0.f;
        #pragma unroll
        for (int cb = 0; cb < 8; ++cb) {
            bf16x8 w8 = *(const bf16x8*)&wb[oc * 576 + kt * 64 + cb * 8];
            #pragma unroll
            for (int i = 0; i < 8; ++i)
                cs += bf2f((ushort)w8[i]) * U[(cb * 8 + i) * 9 + kt];
        }
        gp[tid] = cs;
    }
    __syncthreads();
    if (tid < 64) {
        if (tid < 48) {
            float cs = 0.f;
            #pragma unroll
            for (int kt = 0; kt < 9; ++kt) cs += gp[tid * 9 + kt];
            float a = tg[tid] * rsbn;
            float cb_ = tcn_b[tid] * a + tb[tid];
            seL[tid] = (a * cs + 1600.f * cb_ + SS[tid]) * (1.f / 1600.f);
        } else {
            seL[tid] = (sepS[tid - 48] + SS[tid]) * (1.f / 1600.f);
        }
    }
    __syncthreads();
    if (tid < 32) {
        float a = fc1b[tid];
        #pragma unroll
        for (int c = 0; c < 64; ++c) a += fc1w[tid * 64 + c] * seL[c];
        hid[tid] = fmaxf(a, 0.f);
    }
    __syncthreads();
    if (tid < 64) {
        float g = fc2b[tid];
        #pragma unroll
        for (int j = 0; j < 32; ++j) g += fc2w[tid * 32 + j] * hid[j];
        gateG[n * 64 + tid] = 1.f / (1.f + __expf(-g));
    }
}

// ---------------------------------------------------------------------------
// K2: tcn MFMA + merged final phase — round-10 version (grid 256, split-K
// halves, xsl 600x38). The 512-block split (round 11) measured WORSE
// (49.6us, latency/halo-bound); this version never surfaced in top-5
// (< 43.6us).
// ---------------------------------------------------------------------------
__global__ __launch_bounds__(512, 4) void tcn_mfma_kernel(
    const ushort* __restrict__ rt, const float* __restrict__ x,
    const ushort* __restrict__ wb,
    const float* __restrict__ tcn_b, const float* __restrict__ tg,
    const float* __restrict__ tb,
    const float* __restrict__ gateG, const float* __restrict__ aoc,
    const float* __restrict__ bng, const float* __restrict__ bnb,
    float* __restrict__ out)
{
    __shared__ ushort xsl[600 * 38];     // 45,600 B
    __shared__ float gateL[64];

    const int b = blockIdx.x;
    const int n = b >> 2, tile = b & 3;
    const int t0 = tile * 16;
    const int tid = threadIdx.x;
    const float rsbn = rsqrtf(1.f + 1e-5f);
    const int tvbase = (t0 - 4) * 25;

    if (tid < 64) gateL[tid] = gateG[n * 64 + tid];

    const int lane = tid & 63, wave = tid >> 6;
    const int m16 = lane & 15, q = lane >> 4;
    const int nt0 = wave * 3;

    f32x4 acc[3][3];
    f32x4 acc24[3];
    #pragma unroll
    for (int i = 0; i < 3; ++i)
        #pragma unroll
        for (int mt = 0; mt < 3; ++mt)
            acc[i][mt] = (f32x4){0.f, 0.f, 0.f, 0.f};
    #pragma unroll
    for (int mt = 0; mt < 3; ++mt) acc24[mt] = (f32x4){0.f, 0.f, 0.f, 0.f};

    #pragma unroll 1
    for (int hf = 0; hf < 2; ++hf) {
        if (hf) __syncthreads();         // all reads of previous half done
        for (int idx = tid; idx < 2400; idx += 512) {
            int r = idx >> 2, part = idx & 3;
            int tv = tvbase + r;
            uint4 val = make_uint4(0u, 0u, 0u, 0u);
            if (tv >= 0 && tv < TV_) val = *(const uint4*)&rt[(n * TV_ + tv) * 64 + hf * 32 + part * 8];
            *(uint4*)&xsl[r * 38 + part * 8] = val;
        }
        __syncthreads();
        #pragma unroll 1
        for (int kt = 0; kt < 9; ++kt) {
            const int ktile = kt * 2 + hf;
            bf16x8 afr[3];
            #pragma unroll
            for (int mt = 0; mt < 3; ++mt)
                afr[mt] = *(const bf16x8*)&wb[(mt * 16 + m16) * 576 + ktile * 32 + q * 8];
            #pragma unroll
            for (int i = 0; i < 3; ++i) {
                int p = (nt0 + i) * 16 + m16;
                bf16x8 bfr = *(const bf16x8*)&xsl[(p + kt * 25) * 38 + q * 8];
                #pragma unroll
                for (int mt = 0; mt < 3; ++mt)
                    acc[i][mt] = __builtin_amdgcn_mfma_f32_16x16x32_bf16(afr[mt], bfr, acc[i][mt], 0, 0, 0);
            }
            if (wave == 0) {
                int p = 24 * 16 + m16;
                bf16x8 bfr = *(const bf16x8*)&xsl[(p + kt * 25) * 38 + q * 8];
                #pragma unroll
                for (int mt = 0; mt < 3; ++mt)
                    acc24[mt] = __builtin_amdgcn_mfma_f32_16x16x32_bf16(afr[mt], bfr, acc24[mt], 0, 0, 0);
            }
        }
    }

    #pragma unroll
    for (int mt = 0; mt < 3; ++mt) {
        #pragma unroll
        for (int r = 0; r < 4; ++r) {
            int oc = mt * 16 + q * 4 + r;
            float a = tg[oc] * rsbn;
            float cb_ = tcn_b[oc] * a + tb[oc];
            float mm = (1.f + gateL[oc]) * (bng[oc] * rsbn);
            float bb = bnb[oc];
            #pragma unroll
            for (int i = 0; i < 3; ++i) {
                int posg = tile * 400 + (nt0 + i) * 16 + m16;
                float val = acc[i][mt][r] + cb_ + x[(n * 64 + oc) * TV_ + posg];
                out[(n * 64 + oc) * TV_ + posg] = fmaxf(val * mm + bb, 0.f);
            }
            if (wave == 0) {
                int posg = tile * 400 + 24 * 16 + m16;
                float val = acc24[mt][r] + cb_ + x[(n * 64 + oc) * TV_ + posg];
                out[(n * 64 + oc) * TV_ + posg] = fmaxf(val * mm + bb, 0.f);
            }
        }
    }

    __syncthreads();                 // xsl dead -> reuse as ts[v][o][lt], stride 257
    float* ts = (float*)xsl;         // 25*257 = 6425 floats
    for (int task = tid; task < 1600; task += 512) {
        int v = task >> 6;           // 0..24
        int r = task & 63;
        int o = r >> 2, f = r & 3;
        float4 d = *(const float4*)&aoc[(n * 25 + v) * 1024 + o * 64 + tile * 16 + f * 4];
        float* dst = &ts[v * 257 + o * 16 + f * 4];
        dst[0] = d.x; dst[1] = d.y; dst[2] = d.z; dst[3] = d.w;
    }
    __syncthreads();
    for (int p4 = tid; p4 < 1600; p4 += 512) {   // 16 o x 100 float4
        int o = p4 / 100, r4 = p4 - o * 100;
        int base4 = (n * 64 + 48 + o) * 400 + tile * 100 + r4;
        float4 xr = ((const float4*)x)[base4];
        float4 val;
        #pragma unroll
        for (int e = 0; e < 4; ++e) {
            int pos = r4 * 4 + e;                // 0..399 within tile
            int lt = pos / 25, v = pos - lt * 25;
            ((float*)&val)[e] = ts[v * 257 + o * 16 + lt];
        }
        float mm = (1.f + gateL[48 + o]) * (bng[48 + o] * rsbn);
        float bb = bnb[48 + o];
        val.x = fmaxf((val.x + xr.x) * mm + bb, 0.f);
        val.y = fmaxf((val.y + xr.y) * mm + bb, 0.f);
        val.z = fmaxf((val.z + xr.z) * mm + bb, 0.f);
        val.w = fmaxf((val.w + xr.w) * mm + bb, 0.f);
        ((float4*)out)[base4] = val;
    }
}

extern "C" void kernel_launch(void* const* d_in, const int* in_sizes, int n_in,
                              void* d_out, int out_size, void* d_ws, size_t ws_size,
                              hipStream_t stream) {
    const float* x     = (const float*)d_in[0];
    const float* pe    = (const float*)d_in[1];
    const float* dbg   = (const float*)d_in[2];
    const float* dbb   = (const float*)d_in[3];
    const float* qkvw  = (const float*)d_in[4];
    const float* qkvb  = (const float*)d_in[5];
    const float* attnw = (const float*)d_in[6];
    const float* attnb = (const float*)d_in[7];
    const float* tcnw  = (const float*)d_in[8];
    const float* tcnb  = (const float*)d_in[9];
    const float* tcng  = (const float*)d_in[10];
    const float* tcnbb = (const float*)d_in[11];
    const float* fc1w  = (const float*)d_in[12];
    const float* fc1b  = (const float*)d_in[13];
    const float* fc2w  = (const float*)d_in[14];
    const float* fc2b  = (const float*)d_in[15];
    const float* bng   = (const float*)d_in[16];
    const float* bnb   = (const float*)d_in[17];

    float* out  = (float*)d_out;
    float* Sp   = (float*)d_ws;                      // 64*25*64 = 102400 f
    float* sep  = Sp + 102400;                       // 64*25*16 = 25600 f
    float* Tt   = sep + 25600;                       // 32768 f
    float* qb   = Tt + 32768;                        // 96 f
    float* aoc  = qb + 96;                           // 1,638,400 f
    ushort* wb  = (ushort*)(aoc + 1638400);          // 27648 u16
    ushort* wq  = wb + 27648;                        // 5120 u16
    ushort* pet = wq + 5120;                         // 102,400 u16
    ushort* rt  = pet + 102400;                      // 6,553,600 u16
    float* gateG = (float*)(rt + 6553600);           // 4096 f
    float* dbs  = gateG + 4096;                      // 3200 f

    t1_kernel<<<dim3(27, 64), dim3(256), 0, stream>>>(
        x, pe, tcnw, tcng, qkvw, qkvb, dbg, dbb, rt, Sp, Tt, wb, wq, qb, pet, dbs);
    score_kernel<<<dim3(1600), dim3(256), 0, stream>>>(rt, pet, dbs, wq, qb, attnw, attnb, aoc, sep);
    gate_kernel<<<dim3(64), dim3(256), 0, stream>>>(
        Sp, Tt, sep, wb, tcnb, tcng, tcnbb, fc1w, fc1b, fc2w, fc2b, gateG);
    tcn_mfma_kernel<<<dim3(256), dim3(512), 0, stream>>>(
        rt, x, wb, tcnb, tcng, tcnbb, gateG, aoc, bng, bnb, out);
}